// Round 10
// baseline (386.367 us; speedup 1.0000x reference)
//
#include <hip/hip_runtime.h>
#include <hip/hip_bf16.h>

// Symmetric contraction (MACE-style), B=2048, C=256, I=9, E=10. fp32 only
// (fp32 absmax 0.5 on |out|~450 => sum|terms|/|out| ~1e4; any low-precision
// path is numerically dead -> fp32 VALU roofline at throttled ~1.5 GHz).
//
// Round-10 = r9 (256-thr blocks, intra-block 4-way wave split, validated
// 75% busy) + 2x OVERSUBSCRIPTION: 2048 blocks; each (8b x 64c) tile done by
// two blocks (half0: tri [0,110); half1: tri [110,165)+pairs+singles), all 8
// wave-segments 27-28 row-units. half0 -> pout, half1 -> out, float4 combine
// (r7 infra; NO atomics - r6 lesson). Evidence: r2 packed ~3.8 blocks/CU at
// 2x oversub; r9 packed only ~1.6 at 1x. Inner loop unchanged (r5 lesson).
// prep reverted to (219,10) grid (r4-measured ~20us faster than e-loop prep).

#define NB 2048
#define NC 256
#define NI 9
#define NE 10

#define N_TRI 165
#define N_PAIR 45
#define BT 8

// T layout (float4): T3 [165][10][256] | T2 [45][10][256] | T1 [9][10][256]
#define T3N (N_TRI * NE * NC)
#define T2N (N_PAIR * NE * NC)
#define T1N (NI * NE * NC)
#define TBYTES ((size_t)(T3N + T2N + T1N) * 16)   // 8,970,240 B

// ---------------- prep: Sym (LDS) x W -> T, grid (219, 10) ----------------
__global__ __launch_bounds__(256) void sc_prep(
    const float* __restrict__ U1_s, const float* __restrict__ U2_s,
    const float* __restrict__ U3_s, const float* __restrict__ U1_v,
    const float* __restrict__ U2_v, const float* __restrict__ U3_v,
    const float* __restrict__ W1_s, const float* __restrict__ W2_s,
    const float* __restrict__ W3_s, const float* __restrict__ W1_v,
    const float* __restrict__ W2_v, const float* __restrict__ W3_v,
    float* __restrict__ ws)
{
    const int m = blockIdx.x;    // 0..218
    const int e = blockIdx.y;    // 0..9
    const int tid = threadIdx.x; // 0..255
    float4* __restrict__ T3 = (float4*)ws;
    float4* __restrict__ T2 = T3 + T3N;
    float4* __restrict__ T1 = T2 + T2N;

    __shared__ float sym[128];

    if (m < N_TRI) {
        if (tid < 113) {
            int ii = 0, jj = 0, kk = 0, cnt = 0;
            for (int i = 0; i < NI; i++)
                for (int j = i; j < NI; j++)
                    for (int k = j; k < NI; k++) {
                        if (cnt == m) { ii = i; jj = j; kk = k; }
                        cnt++;
                    }
            int P[6][3]; int np;
            if (ii == jj && jj == kk) {
                np = 1;
                P[0][0] = ii; P[0][1] = ii; P[0][2] = ii;
            } else if (ii == jj) {
                np = 3;
                P[0][0] = ii; P[0][1] = ii; P[0][2] = kk;
                P[1][0] = ii; P[1][1] = kk; P[1][2] = ii;
                P[2][0] = kk; P[2][1] = ii; P[2][2] = ii;
            } else if (jj == kk) {
                np = 3;
                P[0][0] = ii; P[0][1] = jj; P[0][2] = jj;
                P[1][0] = jj; P[1][1] = ii; P[1][2] = jj;
                P[2][0] = jj; P[2][1] = jj; P[2][2] = ii;
            } else {
                np = 6;
                P[0][0] = ii; P[0][1] = jj; P[0][2] = kk;
                P[1][0] = ii; P[1][1] = kk; P[1][2] = jj;
                P[2][0] = jj; P[2][1] = ii; P[2][2] = kk;
                P[3][0] = jj; P[3][1] = kk; P[3][2] = ii;
                P[4][0] = kk; P[4][1] = ii; P[4][2] = jj;
                P[5][0] = kk; P[5][1] = jj; P[5][2] = ii;
            }
            float s = 0.f;
            if (tid < 23) {
                for (int p = 0; p < np; p++)
                    s += U3_s[((P[p][0] * NI + P[p][1]) * NI + P[p][2]) * 23 + tid];
            } else {
                int a = (tid - 23) / 30, t = (tid - 23) % 30;
                for (int p = 0; p < np; p++)
                    s += U3_v[(((a * NI + P[p][0]) * NI + P[p][1]) * NI + P[p][2]) * 30 + t];
            }
            sym[tid] = s;
        }
        __syncthreads();
        const int c = tid;
        float s = 0.f, v0 = 0.f, v1 = 0.f, v2 = 0.f;
        #pragma unroll
        for (int t = 0; t < 23; t++)
            s = fmaf(sym[t], W3_s[(e * 23 + t) * NC + c], s);
        #pragma unroll
        for (int t = 0; t < 30; t++) {
            float wv = W3_v[(e * 30 + t) * NC + c];
            v0 = fmaf(sym[23 + t], wv, v0);
            v1 = fmaf(sym[53 + t], wv, v1);
            v2 = fmaf(sym[83 + t], wv, v2);
        }
        T3[(m * NE + e) * NC + c] = make_float4(s, v0, v1, v2);
    } else if (m < N_TRI + N_PAIR) {
        const int mm = m - N_TRI;
        if (tid < 15) {
            int ii = 0, jj = 0, cnt = 0;
            for (int i = 0; i < NI; i++)
                for (int j = i; j < NI; j++) {
                    if (cnt == mm) { ii = i; jj = j; }
                    cnt++;
                }
            float s;
            if (tid < 3) {
                s = U2_s[(ii * NI + jj) * 3 + tid];
                if (ii != jj) s += U2_s[(jj * NI + ii) * 3 + tid];
            } else {
                int a = (tid - 3) / 4, t = (tid - 3) % 4;
                s = U2_v[((a * NI + ii) * NI + jj) * 4 + t];
                if (ii != jj) s += U2_v[((a * NI + jj) * NI + ii) * 4 + t];
            }
            sym[tid] = s;
        }
        __syncthreads();
        const int c = tid;
        float s = 0.f, v0 = 0.f, v1 = 0.f, v2 = 0.f;
        #pragma unroll
        for (int t = 0; t < 3; t++)
            s = fmaf(sym[t], W2_s[(e * 3 + t) * NC + c], s);
        #pragma unroll
        for (int t = 0; t < 4; t++) {
            float wv = W2_v[(e * 4 + t) * NC + c];
            v0 = fmaf(sym[3 + t],  wv, v0);
            v1 = fmaf(sym[7 + t],  wv, v1);
            v2 = fmaf(sym[11 + t], wv, v2);
        }
        T2[(mm * NE + e) * NC + c] = make_float4(s, v0, v1, v2);
    } else {
        const int i = m - N_TRI - N_PAIR;
        const int c = tid;
        float w1s = W1_s[e * NC + c], w1v = W1_v[e * NC + c];
        T1[(i * NE + e) * NC + c] = make_float4(
            U1_s[i] * w1s,
            U1_v[0 * NI + i] * w1v,
            U1_v[1 * NI + i] * w1v,
            U1_v[2 * NI + i] * w1v);
    }
}

// ---------------- main ----------------
__device__ __forceinline__ void tri_advance(int& i, int& j, int& k) {
    k++;
    if (k == NI) { j++; if (j == NI) { i++; j = i; } k = j; }
}

#define ROW_FMA(BUF)                                              \
    {                                                             \
        _Pragma("unroll")                                         \
        for (int e = 0; e < NE; e++) {                            \
            const float4 t = BUF[e];                              \
            _Pragma("unroll")                                     \
            for (int n = 0; n < BT; n++) {                        \
                const float p = w[e][n] * phi[n];                 \
                acc[n][0] = fmaf(p, t.x, acc[n][0]);              \
                acc[n][1] = fmaf(p, t.y, acc[n][1]);              \
                acc[n][2] = fmaf(p, t.z, acc[n][2]);              \
                acc[n][3] = fmaf(p, t.w, acc[n][3]);              \
            }                                                     \
        }                                                         \
    }

template <int M0, int M1, int I0, int J0, int K0>
__device__ __forceinline__ void do_triples(
    const float4* __restrict__ T3, int c, const float* __restrict__ xb,
    const float (&w)[NE][BT], float (&acc)[BT][4])
{
    float4 bufA[NE], bufB[NE];
    #pragma unroll
    for (int e = 0; e < NE; e++) bufA[e] = T3[(M0 * NE + e) * NC + c];
    int i = I0, j = J0, k = K0;
    for (int m = M0; m + 1 < M1; m += 2) {
        #pragma unroll
        for (int e = 0; e < NE; e++) bufB[e] = T3[((m + 1) * NE + e) * NC + c];
        {
            float phi[BT];
            #pragma unroll
            for (int n = 0; n < BT; n++)
                phi[n] = xb[(i * BT + n) * 64] * xb[(j * BT + n) * 64]
                       * xb[(k * BT + n) * 64];
            ROW_FMA(bufA)
        }
        tri_advance(i, j, k);
        const int mp = (m + 2 < M1) ? m + 2 : M1 - 1;
        #pragma unroll
        for (int e = 0; e < NE; e++) bufA[e] = T3[(mp * NE + e) * NC + c];
        {
            float phi[BT];
            #pragma unroll
            for (int n = 0; n < BT; n++)
                phi[n] = xb[(i * BT + n) * 64] * xb[(j * BT + n) * 64]
                       * xb[(k * BT + n) * 64];
            ROW_FMA(bufB)
        }
        tri_advance(i, j, k);
    }
    if ((M1 - M0) & 1) {
        float phi[BT];
        #pragma unroll
        for (int n = 0; n < BT; n++)
            phi[n] = xb[(i * BT + n) * 64] * xb[(j * BT + n) * 64]
                   * xb[(k * BT + n) * 64];
        ROW_FMA(bufA)
    }
}

template <int M0, int M1, int I0, int J0>
__device__ __forceinline__ void do_pairs(
    const float4* __restrict__ T2, int c, const float* __restrict__ xb,
    const float (&w)[NE][BT], float (&acc)[BT][4])
{
    float4 bufA[NE], bufB[NE];
    #pragma unroll
    for (int e = 0; e < NE; e++) bufA[e] = T2[(M0 * NE + e) * NC + c];
    int i = I0, j = J0;
    for (int m = M0; m + 1 < M1; m += 2) {
        #pragma unroll
        for (int e = 0; e < NE; e++) bufB[e] = T2[((m + 1) * NE + e) * NC + c];
        {
            float phi[BT];
            #pragma unroll
            for (int n = 0; n < BT; n++)
                phi[n] = xb[(i * BT + n) * 64] * xb[(j * BT + n) * 64];
            ROW_FMA(bufA)
        }
        j++; if (j == NI) { i++; j = i; }
        const int mp = (m + 2 < M1) ? m + 2 : M1 - 1;
        #pragma unroll
        for (int e = 0; e < NE; e++) bufA[e] = T2[(mp * NE + e) * NC + c];
        {
            float phi[BT];
            #pragma unroll
            for (int n = 0; n < BT; n++)
                phi[n] = xb[(i * BT + n) * 64] * xb[(j * BT + n) * 64];
            ROW_FMA(bufB)
        }
        j++; if (j == NI) { i++; j = i; }
    }
    if ((M1 - M0) & 1) {
        float phi[BT];
        #pragma unroll
        for (int n = 0; n < BT; n++)
            phi[n] = xb[(i * BT + n) * 64] * xb[(j * BT + n) * 64];
        ROW_FMA(bufA)
    }
}

__device__ __forceinline__ void do_singles(
    const float4* __restrict__ T1, int c, const float* __restrict__ xb,
    const float (&w)[NE][BT], float (&acc)[BT][4])
{
    for (int i = 0; i < NI; i++) {
        float4 tc[NE];
        #pragma unroll
        for (int e = 0; e < NE; e++) tc[e] = T1[(i * NE + e) * NC + c];
        float phi[BT];
        #pragma unroll
        for (int n = 0; n < BT; n++) phi[n] = xb[(i * BT + n) * 64];
        ROW_FMA(tc)
    }
}

// 2048 blocks x 256 thr (4 waves). Two blocks per (8b x 64c) tile:
//   half0: tri [0,27)(0,0,0) | [27,55)(0,3,6) | [55,83)(1,2,4) | [83,110)(2,2,4)
//   half1: tri [110,138)(3,3,4) | [138,165)(4,5,8) | pairs [0,27)(0,0) |
//          pairs [27,45)(3,6) + singles
// All 8 segments 27-28 row-units. half0 -> pout, half1 -> out.
__global__ __launch_bounds__(256) void sc_main_split(
    const float* __restrict__ x, const float* __restrict__ y,
    const float* __restrict__ ws, float* __restrict__ out,
    float* __restrict__ pout)
{
    const int tid = threadIdx.x;
    const int tx  = tid & 63;
    const int wv  = __builtin_amdgcn_readfirstlane(tid >> 6);  // 0..3
    const int bx  = blockIdx.x;
    const int xcd    = bx & 7;
    const int c_tile = xcd >> 1;                 // XCD pair owns one c-slice
    const int half   = (bx >> 3) & 1;
    const int b_tile = ((bx >> 4) << 1) | (xcd & 1);   // 0..255
    const int c0 = c_tile << 6;
    const int c  = c0 + tx;
    const int b0 = b_tile << 3;

    __shared__ float xs[NI][BT][64];    // 18.4 KB shared by all 4 waves
    __shared__ float red[BT][4][64];    //  8.2 KB ping-pong combine

    #pragma unroll
    for (int p = 0; p < 2; p++) {
        const int pair = tid + p * 256;
        const int n = pair >> 6, cc = pair & 63;
        const float* xp = x + ((size_t)(b0 + n) * NC + c0 + cc) * NI;
        #pragma unroll
        for (int i = 0; i < NI; i++) xs[i][n][cc] = xp[i];
    }
    __syncthreads();
    const float* xb = &xs[0][0][tx];

    float w[NE][BT];
    #pragma unroll
    for (int n = 0; n < BT; n++)
        #pragma unroll
        for (int e = 0; e < NE; e++) w[e][n] = y[(b0 + n) * NE + e];

    float acc[BT][4];
    #pragma unroll
    for (int n = 0; n < BT; n++)
        #pragma unroll
        for (int h = 0; h < 4; h++) acc[n][h] = 0.f;

    const float4* __restrict__ T3 = (const float4*)ws;
    const float4* __restrict__ T2 = T3 + T3N;
    const float4* __restrict__ T1 = T2 + T2N;

    if (half == 0) {
        if      (wv == 0) do_triples<0,   27, 0, 0, 0>(T3, c, xb, w, acc);
        else if (wv == 1) do_triples<27,  55, 0, 3, 6>(T3, c, xb, w, acc);
        else if (wv == 2) do_triples<55,  83, 1, 2, 4>(T3, c, xb, w, acc);
        else              do_triples<83, 110, 2, 2, 4>(T3, c, xb, w, acc);
    } else {
        if      (wv == 0) do_triples<110, 138, 3, 3, 4>(T3, c, xb, w, acc);
        else if (wv == 1) do_triples<138, 165, 4, 5, 8>(T3, c, xb, w, acc);
        else if (wv == 2) do_pairs<0, 27, 0, 0>(T2, c, xb, w, acc);
        else {
            do_pairs<27, 45, 3, 6>(T2, c, xb, w, acc);
            do_singles(T1, c, xb, w, acc);
        }
    }

    // serial ping-pong combine: wv0 -> wv1 -> wv2 -> wv3 stores
    if (wv == 0) {
        #pragma unroll
        for (int n = 0; n < BT; n++)
            #pragma unroll
            for (int h = 0; h < 4; h++) red[n][h][tx] = acc[n][h];
    }
    __syncthreads();
    if (wv == 1) {
        #pragma unroll
        for (int n = 0; n < BT; n++)
            #pragma unroll
            for (int h = 0; h < 4; h++) acc[n][h] += red[n][h][tx];
    }
    __syncthreads();
    if (wv == 1) {
        #pragma unroll
        for (int n = 0; n < BT; n++)
            #pragma unroll
            for (int h = 0; h < 4; h++) red[n][h][tx] = acc[n][h];
    }
    __syncthreads();
    if (wv == 2) {
        #pragma unroll
        for (int n = 0; n < BT; n++)
            #pragma unroll
            for (int h = 0; h < 4; h++) acc[n][h] += red[n][h][tx];
    }
    __syncthreads();
    if (wv == 2) {
        #pragma unroll
        for (int n = 0; n < BT; n++)
            #pragma unroll
            for (int h = 0; h < 4; h++) red[n][h][tx] = acc[n][h];
    }
    __syncthreads();
    if (wv == 3) {
        float* __restrict__ dst = half ? out : pout;
        #pragma unroll
        for (int n = 0; n < BT; n++) {
            float* ob = dst + (size_t)(b0 + n) * (4 * NC);
            ob[c]              = acc[n][0] + red[n][0][tx];
            ob[NC + 3 * c + 0] = acc[n][1] + red[n][1][tx];
            ob[NC + 3 * c + 1] = acc[n][2] + red[n][2][tx];
            ob[NC + 3 * c + 2] = acc[n][3] + red[n][3][tx];
        }
    }
}

// fallback (ws too small): r9's 1024-block full kernel
__global__ __launch_bounds__(256) void sc_main_full(
    const float* __restrict__ x, const float* __restrict__ y,
    const float* __restrict__ ws, float* __restrict__ out)
{
    const int tid = threadIdx.x;
    const int tx  = tid & 63;
    const int wv  = __builtin_amdgcn_readfirstlane(tid >> 6);
    const int bid = blockIdx.x;
    const int xcd    = bid & 7;
    const int c_tile = xcd >> 1;
    const int b_tile = ((bid >> 3) << 1) | (xcd & 1);
    const int c0 = c_tile << 6;
    const int c  = c0 + tx;
    const int b0 = b_tile << 3;

    __shared__ float xs[NI][BT][64];
    __shared__ float red[BT][4][64];

    #pragma unroll
    for (int p = 0; p < 2; p++) {
        const int pair = tid + p * 256;
        const int n = pair >> 6, cc = pair & 63;
        const float* xp = x + ((size_t)(b0 + n) * NC + c0 + cc) * NI;
        #pragma unroll
        for (int i = 0; i < NI; i++) xs[i][n][cc] = xp[i];
    }
    __syncthreads();
    const float* xb = &xs[0][0][tx];

    float w[NE][BT];
    #pragma unroll
    for (int n = 0; n < BT; n++)
        #pragma unroll
        for (int e = 0; e < NE; e++) w[e][n] = y[(b0 + n) * NE + e];

    float acc[BT][4];
    #pragma unroll
    for (int n = 0; n < BT; n++)
        #pragma unroll
        for (int h = 0; h < 4; h++) acc[n][h] = 0.f;

    const float4* __restrict__ T3 = (const float4*)ws;
    const float4* __restrict__ T2 = T3 + T3N;
    const float4* __restrict__ T1 = T2 + T2N;

    if      (wv == 0) do_triples<0,   55, 0, 0, 0>(T3, c, xb, w, acc);
    else if (wv == 1) do_triples<55, 110, 1, 2, 4>(T3, c, xb, w, acc);
    else if (wv == 2) do_triples<110, N_TRI, 3, 3, 4>(T3, c, xb, w, acc);
    else {
        do_pairs<0, N_PAIR, 0, 0>(T2, c, xb, w, acc);
        do_singles(T1, c, xb, w, acc);
    }

    if (wv == 0) {
        #pragma unroll
        for (int n = 0; n < BT; n++)
            #pragma unroll
            for (int h = 0; h < 4; h++) red[n][h][tx] = acc[n][h];
    }
    __syncthreads();
    if (wv == 1) {
        #pragma unroll
        for (int n = 0; n < BT; n++)
            #pragma unroll
            for (int h = 0; h < 4; h++) acc[n][h] += red[n][h][tx];
    }
    __syncthreads();
    if (wv == 1) {
        #pragma unroll
        for (int n = 0; n < BT; n++)
            #pragma unroll
            for (int h = 0; h < 4; h++) red[n][h][tx] = acc[n][h];
    }
    __syncthreads();
    if (wv == 2) {
        #pragma unroll
        for (int n = 0; n < BT; n++)
            #pragma unroll
            for (int h = 0; h < 4; h++) acc[n][h] += red[n][h][tx];
    }
    __syncthreads();
    if (wv == 2) {
        #pragma unroll
        for (int n = 0; n < BT; n++)
            #pragma unroll
            for (int h = 0; h < 4; h++) red[n][h][tx] = acc[n][h];
    }
    __syncthreads();
    if (wv == 3) {
        #pragma unroll
        for (int n = 0; n < BT; n++) {
            float* ob = out + (size_t)(b0 + n) * (4 * NC);
            ob[c]              = acc[n][0] + red[n][0][tx];
            ob[NC + 3 * c + 0] = acc[n][1] + red[n][1][tx];
            ob[NC + 3 * c + 1] = acc[n][2] + red[n][2][tx];
            ob[NC + 3 * c + 2] = acc[n][3] + red[n][3][tx];
        }
    }
}

// out += partial (float4)
__global__ __launch_bounds__(256) void sc_combine(
    float4* __restrict__ out, const float4* __restrict__ p, int n4)
{
    int i = blockIdx.x * 256 + threadIdx.x;
    if (i < n4) {
        float4 a = out[i], b = p[i];
        out[i] = make_float4(a.x + b.x, a.y + b.y, a.z + b.z, a.w + b.w);
    }
}

extern "C" void kernel_launch(void* const* d_in, const int* in_sizes, int n_in,
                              void* d_out, int out_size, void* d_ws, size_t ws_size,
                              hipStream_t stream) {
    const float* x    = (const float*)d_in[0];
    const float* y    = (const float*)d_in[1];
    const float* U1_s = (const float*)d_in[2];
    const float* U2_s = (const float*)d_in[3];
    const float* U3_s = (const float*)d_in[4];
    const float* U1_v = (const float*)d_in[5];
    const float* U2_v = (const float*)d_in[6];
    const float* U3_v = (const float*)d_in[7];
    const float* W1_s = (const float*)d_in[8];
    const float* W2_s = (const float*)d_in[9];
    const float* W3_s = (const float*)d_in[10];
    const float* W1_v = (const float*)d_in[11];
    const float* W2_v = (const float*)d_in[12];
    const float* W3_v = (const float*)d_in[13];
    float* out = (float*)d_out;
    float* ws  = (float*)d_ws;   // T (8.97 MB) + partial (8.4 MB)

    sc_prep<<<dim3(N_TRI + N_PAIR + NI, NE), 256, 0, stream>>>(
        U1_s, U2_s, U3_s, U1_v, U2_v, U3_v,
        W1_s, W2_s, W3_s, W1_v, W2_v, W3_v, ws);

    const size_t out_bytes = (size_t)out_size * sizeof(float);
    if (ws_size >= TBYTES + out_bytes) {
        float* pout = (float*)((char*)d_ws + TBYTES);
        sc_main_split<<<2048, 256, 0, stream>>>(x, y, ws, out, pout);
        const int n4 = out_size / 4;
        sc_combine<<<(n4 + 255) / 256, 256, 0, stream>>>(
            (float4*)out, (const float4*)pout, n4);
    } else {
        sc_main_full<<<1024, 256, 0, stream>>>(x, y, ws, out);
    }
}

// Round 11
// 265.079 us; speedup vs baseline: 1.4576x; 1.4576x over previous
//
#include <hip/hip_runtime.h>
#include <hip/hip_bf16.h>

// Symmetric contraction (MACE-style), B=2048, C=256, I=9, E=10. fp32 only
// (fp32 absmax 0.5 on |out|~450 => sum|terms|/|out| ~1e4; low precision dead).
//
// Round-11 = round-9 main kernel VERBATIM (best measured: 182us main, VGPR 92,
// 4 waves/SIMD allowed, VALUBusy 75%) + (219,10)-grid prep (r4-measured ~25us
// faster than e-loop prep).
// Ledger of measured lessons:
//  r2: no waves/EU launch-bounds cap (spills). r5: don't restructure ROW_FMA.
//  r6: no global-atomic combine. r8: LDS size isn't the residency lever.
//  r9: 256-thr blocks pack CUs; 128-thr don't. r10: keep VGPR <= 128 --
//      code-path merging cost 172 VGPR -> waves/SIMD halved -> 1.75x slower.

#define NB 2048
#define NC 256
#define NI 9
#define NE 10

#define N_TRI 165
#define N_PAIR 45
#define BT 8

// T layout (float4): T3 [165][10][256] | T2 [45][10][256] | T1 [9][10][256]
#define T3N (N_TRI * NE * NC)
#define T2N (N_PAIR * NE * NC)
#define T1N (NI * NE * NC)

// ---------------- prep: Sym (LDS) x W -> T, grid (219, 10) ----------------
__global__ __launch_bounds__(256) void sc_prep(
    const float* __restrict__ U1_s, const float* __restrict__ U2_s,
    const float* __restrict__ U3_s, const float* __restrict__ U1_v,
    const float* __restrict__ U2_v, const float* __restrict__ U3_v,
    const float* __restrict__ W1_s, const float* __restrict__ W2_s,
    const float* __restrict__ W3_s, const float* __restrict__ W1_v,
    const float* __restrict__ W2_v, const float* __restrict__ W3_v,
    float* __restrict__ ws)
{
    const int m = blockIdx.x;    // 0..218
    const int e = blockIdx.y;    // 0..9
    const int tid = threadIdx.x; // 0..255
    float4* __restrict__ T3 = (float4*)ws;
    float4* __restrict__ T2 = T3 + T3N;
    float4* __restrict__ T1 = T2 + T2N;

    __shared__ float sym[128];

    if (m < N_TRI) {
        if (tid < 113) {
            int ii = 0, jj = 0, kk = 0, cnt = 0;
            for (int i = 0; i < NI; i++)
                for (int j = i; j < NI; j++)
                    for (int k = j; k < NI; k++) {
                        if (cnt == m) { ii = i; jj = j; kk = k; }
                        cnt++;
                    }
            int P[6][3]; int np;
            if (ii == jj && jj == kk) {
                np = 1;
                P[0][0] = ii; P[0][1] = ii; P[0][2] = ii;
            } else if (ii == jj) {
                np = 3;
                P[0][0] = ii; P[0][1] = ii; P[0][2] = kk;
                P[1][0] = ii; P[1][1] = kk; P[1][2] = ii;
                P[2][0] = kk; P[2][1] = ii; P[2][2] = ii;
            } else if (jj == kk) {
                np = 3;
                P[0][0] = ii; P[0][1] = jj; P[0][2] = jj;
                P[1][0] = jj; P[1][1] = ii; P[1][2] = jj;
                P[2][0] = jj; P[2][1] = jj; P[2][2] = ii;
            } else {
                np = 6;
                P[0][0] = ii; P[0][1] = jj; P[0][2] = kk;
                P[1][0] = ii; P[1][1] = kk; P[1][2] = jj;
                P[2][0] = jj; P[2][1] = ii; P[2][2] = kk;
                P[3][0] = jj; P[3][1] = kk; P[3][2] = ii;
                P[4][0] = kk; P[4][1] = ii; P[4][2] = jj;
                P[5][0] = kk; P[5][1] = jj; P[5][2] = ii;
            }
            float s = 0.f;
            if (tid < 23) {
                for (int p = 0; p < np; p++)
                    s += U3_s[((P[p][0] * NI + P[p][1]) * NI + P[p][2]) * 23 + tid];
            } else {
                int a = (tid - 23) / 30, t = (tid - 23) % 30;
                for (int p = 0; p < np; p++)
                    s += U3_v[(((a * NI + P[p][0]) * NI + P[p][1]) * NI + P[p][2]) * 30 + t];
            }
            sym[tid] = s;
        }
        __syncthreads();
        const int c = tid;
        float s = 0.f, v0 = 0.f, v1 = 0.f, v2 = 0.f;
        #pragma unroll
        for (int t = 0; t < 23; t++)
            s = fmaf(sym[t], W3_s[(e * 23 + t) * NC + c], s);
        #pragma unroll
        for (int t = 0; t < 30; t++) {
            float wv = W3_v[(e * 30 + t) * NC + c];
            v0 = fmaf(sym[23 + t], wv, v0);
            v1 = fmaf(sym[53 + t], wv, v1);
            v2 = fmaf(sym[83 + t], wv, v2);
        }
        T3[(m * NE + e) * NC + c] = make_float4(s, v0, v1, v2);
    } else if (m < N_TRI + N_PAIR) {
        const int mm = m - N_TRI;
        if (tid < 15) {
            int ii = 0, jj = 0, cnt = 0;
            for (int i = 0; i < NI; i++)
                for (int j = i; j < NI; j++) {
                    if (cnt == mm) { ii = i; jj = j; }
                    cnt++;
                }
            float s;
            if (tid < 3) {
                s = U2_s[(ii * NI + jj) * 3 + tid];
                if (ii != jj) s += U2_s[(jj * NI + ii) * 3 + tid];
            } else {
                int a = (tid - 3) / 4, t = (tid - 3) % 4;
                s = U2_v[((a * NI + ii) * NI + jj) * 4 + t];
                if (ii != jj) s += U2_v[((a * NI + jj) * NI + ii) * 4 + t];
            }
            sym[tid] = s;
        }
        __syncthreads();
        const int c = tid;
        float s = 0.f, v0 = 0.f, v1 = 0.f, v2 = 0.f;
        #pragma unroll
        for (int t = 0; t < 3; t++)
            s = fmaf(sym[t], W2_s[(e * 3 + t) * NC + c], s);
        #pragma unroll
        for (int t = 0; t < 4; t++) {
            float wv = W2_v[(e * 4 + t) * NC + c];
            v0 = fmaf(sym[3 + t],  wv, v0);
            v1 = fmaf(sym[7 + t],  wv, v1);
            v2 = fmaf(sym[11 + t], wv, v2);
        }
        T2[(mm * NE + e) * NC + c] = make_float4(s, v0, v1, v2);
    } else {
        const int i = m - N_TRI - N_PAIR;
        const int c = tid;
        float w1s = W1_s[e * NC + c], w1v = W1_v[e * NC + c];
        T1[(i * NE + e) * NC + c] = make_float4(
            U1_s[i] * w1s,
            U1_v[0 * NI + i] * w1v,
            U1_v[1 * NI + i] * w1v,
            U1_v[2 * NI + i] * w1v);
    }
}

// ---------------- main (r9 verbatim) ----------------
__device__ __forceinline__ void tri_advance(int& i, int& j, int& k) {
    k++;
    if (k == NI) { j++; if (j == NI) { i++; j = i; } k = j; }
}

#define ROW_FMA(BUF)                                              \
    {                                                             \
        _Pragma("unroll")                                         \
        for (int e = 0; e < NE; e++) {                            \
            const float4 t = BUF[e];                              \
            _Pragma("unroll")                                     \
            for (int n = 0; n < BT; n++) {                        \
                const float p = w[e][n] * phi[n];                 \
                acc[n][0] = fmaf(p, t.x, acc[n][0]);              \
                acc[n][1] = fmaf(p, t.y, acc[n][1]);              \
                acc[n][2] = fmaf(p, t.z, acc[n][2]);              \
                acc[n][3] = fmaf(p, t.w, acc[n][3]);              \
            }                                                     \
        }                                                         \
    }

template <int M0, int M1, int I0, int J0, int K0>
__device__ __forceinline__ void do_triples(
    const float4* __restrict__ T3, int c, const float* __restrict__ xb,
    const float (&w)[NE][BT], float (&acc)[BT][4])
{
    float4 bufA[NE], bufB[NE];
    #pragma unroll
    for (int e = 0; e < NE; e++) bufA[e] = T3[(M0 * NE + e) * NC + c];
    int i = I0, j = J0, k = K0;
    for (int m = M0; m + 1 < M1; m += 2) {
        #pragma unroll
        for (int e = 0; e < NE; e++) bufB[e] = T3[((m + 1) * NE + e) * NC + c];
        {
            float phi[BT];
            #pragma unroll
            for (int n = 0; n < BT; n++)
                phi[n] = xb[(i * BT + n) * 64] * xb[(j * BT + n) * 64]
                       * xb[(k * BT + n) * 64];
            ROW_FMA(bufA)
        }
        tri_advance(i, j, k);
        const int mp = (m + 2 < M1) ? m + 2 : M1 - 1;
        #pragma unroll
        for (int e = 0; e < NE; e++) bufA[e] = T3[(mp * NE + e) * NC + c];
        {
            float phi[BT];
            #pragma unroll
            for (int n = 0; n < BT; n++)
                phi[n] = xb[(i * BT + n) * 64] * xb[(j * BT + n) * 64]
                       * xb[(k * BT + n) * 64];
            ROW_FMA(bufB)
        }
        tri_advance(i, j, k);
    }
    if ((M1 - M0) & 1) {
        float phi[BT];
        #pragma unroll
        for (int n = 0; n < BT; n++)
            phi[n] = xb[(i * BT + n) * 64] * xb[(j * BT + n) * 64]
                   * xb[(k * BT + n) * 64];
        ROW_FMA(bufA)
    }
}

// grid 1024 x 256 threads (4 waves). One block = one (8b x 64c) tile.
// wv0: tri [0,55)  wv1: tri [55,110)  wv2: tri [110,165)  wv3: pairs+singles.
__global__ __launch_bounds__(256) void sc_main(
    const float* __restrict__ x, const float* __restrict__ y,
    const float* __restrict__ ws, float* __restrict__ out)
{
    const int tid = threadIdx.x;
    const int tx  = tid & 63;
    const int wv  = __builtin_amdgcn_readfirstlane(tid >> 6);  // 0..3, uniform
    const int bid = blockIdx.x;
    const int xcd    = bid & 7;
    const int c_tile = xcd >> 1;               // XCD pair owns one c-slice of T
    const int b_tile = ((bid >> 3) << 1) | (xcd & 1);   // 0..255
    const int c0 = c_tile << 6;
    const int c  = c0 + tx;
    const int b0 = b_tile << 3;                // 8 b's per block, shared

    __shared__ float xs[NI][BT][64];    // 18.4 KB, shared by all 4 waves
    __shared__ float red[BT][4][64];    //  8.2 KB ping-pong combine buffer

    #pragma unroll
    for (int p = 0; p < 2; p++) {
        const int pair = tid + p * 256;
        const int n = pair >> 6, cc = pair & 63;
        const float* xp = x + ((size_t)(b0 + n) * NC + c0 + cc) * NI;
        #pragma unroll
        for (int i = 0; i < NI; i++) xs[i][n][cc] = xp[i];
    }
    __syncthreads();
    const float* xb = &xs[0][0][tx];    // xb[(i*BT+n)*64]

    float w[NE][BT];
    #pragma unroll
    for (int n = 0; n < BT; n++)
        #pragma unroll
        for (int e = 0; e < NE; e++) w[e][n] = y[(b0 + n) * NE + e];

    float acc[BT][4];
    #pragma unroll
    for (int n = 0; n < BT; n++)
        #pragma unroll
        for (int h = 0; h < 4; h++) acc[n][h] = 0.f;

    const float4* __restrict__ T3 = (const float4*)ws;
    const float4* __restrict__ T2 = T3 + T3N;
    const float4* __restrict__ T1 = T2 + T2N;

    if (wv == 0) {
        do_triples<0, 55, 0, 0, 0>(T3, c, xb, w, acc);
    } else if (wv == 1) {
        do_triples<55, 110, 1, 2, 4>(T3, c, xb, w, acc);
    } else if (wv == 2) {
        do_triples<110, N_TRI, 3, 3, 4>(T3, c, xb, w, acc);
    } else {
        // pairs: 45 rows, unroll-2 A/B
        {
            float4 bufA[NE], bufB[NE];
            #pragma unroll
            for (int e = 0; e < NE; e++) bufA[e] = T2[e * NC + c];
            int i = 0, j = 0;
            for (int m = 0; m + 1 < N_PAIR; m += 2) {
                #pragma unroll
                for (int e = 0; e < NE; e++) bufB[e] = T2[((m + 1) * NE + e) * NC + c];
                {
                    float phi[BT];
                    #pragma unroll
                    for (int n = 0; n < BT; n++)
                        phi[n] = xb[(i * BT + n) * 64] * xb[(j * BT + n) * 64];
                    ROW_FMA(bufA)
                }
                j++; if (j == NI) { i++; j = i; }
                const int mp = (m + 2 < N_PAIR) ? m + 2 : N_PAIR - 1;
                #pragma unroll
                for (int e = 0; e < NE; e++) bufA[e] = T2[(mp * NE + e) * NC + c];
                {
                    float phi[BT];
                    #pragma unroll
                    for (int n = 0; n < BT; n++)
                        phi[n] = xb[(i * BT + n) * 64] * xb[(j * BT + n) * 64];
                    ROW_FMA(bufB)
                }
                j++; if (j == NI) { i++; j = i; }
            }
            {   // tail row 44 in bufA
                float phi[BT];
                #pragma unroll
                for (int n = 0; n < BT; n++)
                    phi[n] = xb[(i * BT + n) * 64] * xb[(j * BT + n) * 64];
                ROW_FMA(bufA)
            }
        }
        // singles
        for (int i = 0; i < NI; i++) {
            float4 tc[NE];
            #pragma unroll
            for (int e = 0; e < NE; e++) tc[e] = T1[(i * NE + e) * NC + c];
            float phi[BT];
            #pragma unroll
            for (int n = 0; n < BT; n++) phi[n] = xb[(i * BT + n) * 64];
            ROW_FMA(tc)
        }
    }

    // serial ping-pong combine: wv0 -> wv1 -> wv2 -> wv3 stores.
    if (wv == 0) {
        #pragma unroll
        for (int n = 0; n < BT; n++)
            #pragma unroll
            for (int h = 0; h < 4; h++) red[n][h][tx] = acc[n][h];
    }
    __syncthreads();
    if (wv == 1) {
        #pragma unroll
        for (int n = 0; n < BT; n++)
            #pragma unroll
            for (int h = 0; h < 4; h++) acc[n][h] += red[n][h][tx];
    }
    __syncthreads();
    if (wv == 1) {
        #pragma unroll
        for (int n = 0; n < BT; n++)
            #pragma unroll
            for (int h = 0; h < 4; h++) red[n][h][tx] = acc[n][h];
    }
    __syncthreads();
    if (wv == 2) {
        #pragma unroll
        for (int n = 0; n < BT; n++)
            #pragma unroll
            for (int h = 0; h < 4; h++) acc[n][h] += red[n][h][tx];
    }
    __syncthreads();
    if (wv == 2) {
        #pragma unroll
        for (int n = 0; n < BT; n++)
            #pragma unroll
            for (int h = 0; h < 4; h++) red[n][h][tx] = acc[n][h];
    }
    __syncthreads();
    if (wv == 3) {
        #pragma unroll
        for (int n = 0; n < BT; n++) {
            float* ob = out + (size_t)(b0 + n) * (4 * NC);
            ob[c]              = acc[n][0] + red[n][0][tx];
            ob[NC + 3 * c + 0] = acc[n][1] + red[n][1][tx];
            ob[NC + 3 * c + 1] = acc[n][2] + red[n][2][tx];
            ob[NC + 3 * c + 2] = acc[n][3] + red[n][3][tx];
        }
    }
}

extern "C" void kernel_launch(void* const* d_in, const int* in_sizes, int n_in,
                              void* d_out, int out_size, void* d_ws, size_t ws_size,
                              hipStream_t stream) {
    const float* x    = (const float*)d_in[0];
    const float* y    = (const float*)d_in[1];
    const float* U1_s = (const float*)d_in[2];
    const float* U2_s = (const float*)d_in[3];
    const float* U3_s = (const float*)d_in[4];
    const float* U1_v = (const float*)d_in[5];
    const float* U2_v = (const float*)d_in[6];
    const float* U3_v = (const float*)d_in[7];
    const float* W1_s = (const float*)d_in[8];
    const float* W2_s = (const float*)d_in[9];
    const float* W3_s = (const float*)d_in[10];
    const float* W1_v = (const float*)d_in[11];
    const float* W2_v = (const float*)d_in[12];
    const float* W3_v = (const float*)d_in[13];
    float* out = (float*)d_out;
    float* ws  = (float*)d_ws;   // 8.97 MB T table, rebuilt every call

    sc_prep<<<dim3(N_TRI + N_PAIR + NI, NE), 256, 0, stream>>>(
        U1_s, U2_s, U3_s, U1_v, U2_v, U3_v,
        W1_s, W2_s, W3_s, W1_v, W2_v, W3_v, ws);
    sc_main<<<1024, 256, 0, stream>>>(x, y, ws, out);
}